// Round 1
// baseline (339.356 us; speedup 1.0000x reference)
//
#include <hip/hip_runtime.h>
#include <math.h>

#define Bn  16
#define Tn  8192
#define Dn  128
#define Cn  64
#define Gn  8     // chunks per group
#define NGn 16    // groups per batch
#define GCn 512   // rows per group

__device__ __forceinline__ float sig_(float x){ return 1.0f/(1.0f+expf(-x)); }

// -------------------------------------------------------------------------
// K1: per (b,g): A_g[i][j] = sum_{r<512} lam^{511-r} k_r[i] v_r[j]
//     ksum_g[i] = sum_{r<512} lam^{511-r} k_r[i]   (Horner)
// -------------------------------------------------------------------------
__global__ __launch_bounds__(256)
void k1_group_outer(const float* __restrict__ kin, const float* __restrict__ vin,
                    const float* __restrict__ log_decay,
                    float* __restrict__ A, float* __restrict__ ksumg)
{
    const int g = blockIdx.x, b = blockIdx.y;
    const int tid = threadIdx.x;
    const float lam = sig_(log_decay[0]);

    __shared__ __align__(16) float kb[16*128];
    __shared__ __align__(16) float vb[16*128];
    __shared__ float wt[GCn];

    for (int i = tid; i < GCn; i += 256) wt[i] = powf(lam, (float)(GCn-1-i));

    const size_t base = ((size_t)b*Tn + (size_t)g*GCn)*Dn;
    const float* kg = kin + base;
    const float* vg = vin + base;

    const int ty = tid >> 4;          // 0..15
    const int tx = tid & 15;          // 0..15
    const int i0 = ty*8;              // 8 contiguous k-rows
    const int j0 = tx*4;              // j in {4tx..4tx+3} and {4tx+64..}

    float4 acc0[8], acc1[8];
    #pragma unroll
    for (int a = 0; a < 8; ++a) {
        acc0[a] = make_float4(0.f,0.f,0.f,0.f);
        acc1[a] = make_float4(0.f,0.f,0.f,0.f);
    }

    for (int r0 = 0; r0 < GCn; r0 += 16) {
        __syncthreads();
        #pragma unroll
        for (int it = 0; it < 8; ++it) {
            int idx = tid + it*256;                // 0..2047
            int rr = idx >> 7, d = idx & 127;
            kb[rr*128+d] = wt[r0+rr] * kg[(size_t)(r0+rr)*Dn + d];
            vb[rr*128+d] =             vg[(size_t)(r0+rr)*Dn + d];
        }
        __syncthreads();
        #pragma unroll
        for (int rr = 0; rr < 16; ++rr) {
            float4 v0 = *(const float4*)&vb[rr*128 + j0];
            float4 v1 = *(const float4*)&vb[rr*128 + j0 + 64];
            #pragma unroll
            for (int a = 0; a < 8; ++a) {
                float kv = kb[rr*128 + i0 + a];
                acc0[a].x += kv*v0.x; acc0[a].y += kv*v0.y;
                acc0[a].z += kv*v0.z; acc0[a].w += kv*v0.w;
                acc1[a].x += kv*v1.x; acc1[a].y += kv*v1.y;
                acc1[a].z += kv*v1.z; acc1[a].w += kv*v1.w;
            }
        }
    }
    float* Ab = A + ((size_t)(b*NGn + g))*Dn*Dn;
    #pragma unroll
    for (int a = 0; a < 8; ++a) {
        *(float4*)&Ab[(size_t)(i0+a)*Dn + j0]      = acc0[a];
        *(float4*)&Ab[(size_t)(i0+a)*Dn + j0 + 64] = acc1[a];
    }
    if (tid < Dn) {
        float s = 0.f;
        for (int r = 0; r < GCn; ++r) s = s*lam + kg[(size_t)r*Dn + tid];
        ksumg[((size_t)(b*NGn+g))*Dn + tid] = s;
    }
}

// -------------------------------------------------------------------------
// K2: exclusive scan over groups: Sg[b][g] = state before group g,
//     final carry = final state/z -> written straight to d_out sections.
// -------------------------------------------------------------------------
__global__ __launch_bounds__(256)
void k2_scan(const float* __restrict__ A, const float* __restrict__ ksumg,
             const float* __restrict__ log_decay,
             float* __restrict__ Sg, float* __restrict__ zg,
             float* __restrict__ outState, float* __restrict__ outZ)
{
    const int idx = blockIdx.x*256 + threadIdx.x;
    const float lam = sig_(log_decay[0]);
    const float dG = powf(lam, (float)GCn);
    const int NSTATE = Bn*Dn*Dn;
    if (idx < NSTATE) {
        const int b = idx >> 14, ij = idx & 16383;
        float s = 0.f;
        #pragma unroll
        for (int g = 0; g < NGn; ++g) {
            size_t o = (((size_t)(b*NGn+g)) << 14) + ij;
            Sg[o] = s;
            s = dG*s + A[o];
        }
        outState[idx] = s;
    } else if (idx < NSTATE + Bn*Dn) {
        const int j = idx - NSTATE, b = j >> 7, d = j & 127;
        float s = 0.f;
        #pragma unroll
        for (int g = 0; g < NGn; ++g) {
            size_t o = (size_t)(b*NGn+g)*Dn + d;
            zg[o] = s;
            s = dG*s + ksumg[o];
        }
        outZ[j] = s;
    }
}

// -------------------------------------------------------------------------
// K3: per (b,g): state in LDS, process 8 chunks sequentially.
//   LDS floats: S[128][132] | kT[128][68] (k transposed) | vB[64][128]
//               attn[64][66] | zb[128] | iz[64] | ptab[65]
// -------------------------------------------------------------------------
__global__ __launch_bounds__(512)
void k3_main(const float* __restrict__ qin, const float* __restrict__ kin,
             const float* __restrict__ vin, const float* __restrict__ log_decay,
             const float* __restrict__ Sg, const float* __restrict__ zg,
             float* __restrict__ out)
{
    const int g = blockIdx.x, b = blockIdx.y;
    const int tid = threadIdx.x;
    const float lam = sig_(log_decay[0]);

    __shared__ __align__(16) float sm[38288];
    float* S     = sm;           // 128*132 = 16896
    float* kT    = sm + 16896;   // 128*68  =  8704
    float* vB    = sm + 25600;   // 64*128  =  8192
    float* attnL = sm + 33792;   // 64*66   =  4224
    float* zb    = sm + 38016;   // 128
    float* izb   = sm + 38144;   // 64
    float* ptab  = sm + 38208;   // 65

    // init: load group-start state, z, power table
    {
        const float* Sgp = Sg + (((size_t)(b*NGn + g)) << 14);
        for (int idx = tid; idx < Dn*Dn; idx += 512) {
            int e = idx >> 7, d = idx & 127;
            S[e*132 + d] = Sgp[idx];
        }
        if (tid < Dn) zb[tid] = zg[(size_t)(b*NGn+g)*Dn + tid];
        if (tid < 65) ptab[tid] = powf(lam, (float)tid);
    }

    for (int m = 0; m < Gn; ++m) {
        const size_t rowbase = (size_t)b*Tn + (size_t)(g*Gn + m)*Cn;
        __syncthreads();   // init done / previous phase C done

        // ---- stage k (transposed) and v ----
        {
            const int c = tid & 63, seg = tid >> 6;     // 64 rows x 8 e-segments
            const float* krow = kin + (rowbase + c)*Dn + seg*16;
            #pragma unroll
            for (int u = 0; u < 4; ++u) {
                float4 kk = *(const float4*)(krow + u*4);
                int e = seg*16 + u*4;
                kT[(e+0)*68 + c] = kk.x;
                kT[(e+1)*68 + c] = kk.y;
                kT[(e+2)*68 + c] = kk.z;
                kT[(e+3)*68 + c] = kk.w;
            }
            #pragma unroll
            for (int it = 0; it < 4; ++it) {
                int idx = tid + it*512;                 // 0..2047 float4s
                int cc = idx >> 5, d4 = (idx & 31)*4;
                *(float4*)&vB[cc*128 + d4] =
                    *(const float4*)&vin[(rowbase + cc)*Dn + d4];
            }
        }
        __syncthreads();

        // ---- Phase A: attn[i][j] = (q_i . k_j) * lam^{i-j}, causal ----
        {
            const int ty = tid >> 4, tx = tid & 15;
            const int i0 = ty*2, j0 = tx*4;
            float4 a0 = make_float4(0.f,0.f,0.f,0.f);
            float4 a1 = make_float4(0.f,0.f,0.f,0.f);
            const float* q0 = qin + (rowbase + i0)*Dn;
            const float* q1 = q0 + Dn;
            for (int e0 = 0; e0 < Dn; e0 += 4) {
                float4 qa = *(const float4*)(q0 + e0);
                float4 qb = *(const float4*)(q1 + e0);
                #pragma unroll
                for (int ee = 0; ee < 4; ++ee) {
                    float4 kk = *(const float4*)&kT[(e0+ee)*68 + j0];
                    float qx = (ee==0)?qa.x:(ee==1)?qa.y:(ee==2)?qa.z:qa.w;
                    float qy = (ee==0)?qb.x:(ee==1)?qb.y:(ee==2)?qb.z:qb.w;
                    a0.x += qx*kk.x; a0.y += qx*kk.y; a0.z += qx*kk.z; a0.w += qx*kk.w;
                    a1.x += qy*kk.x; a1.y += qy*kk.y; a1.z += qy*kk.z; a1.w += qy*kk.w;
                }
            }
            float v0[4] = {a0.x,a0.y,a0.z,a0.w};
            float v1[4] = {a1.x,a1.y,a1.z,a1.w};
            #pragma unroll
            for (int jj = 0; jj < 4; ++jj) {
                int j = j0 + jj;
                attnL[(i0  )*66 + j] = (j <= i0  ) ? v0[jj]*ptab[i0-j]   : 0.f;
                attnL[(i0+1)*66 + j] = (j <= i0+1) ? v1[jj]*ptab[i0+1-j] : 0.f;
            }
        }
        __syncthreads();
        if (tid < Cn) {                 // row sums -> iz
            float s = 0.f;
            for (int j = 0; j < Cn; ++j) s += attnL[tid*66 + j];
            izb[tid] = fmaxf(s, 1.0f);
        }
        __syncthreads();

        // ---- Phase B: out = (attn@V + lam^{i+1} q@S) / max(iz + lam^{i+1} q.z, 1) ----
        {
            const int ty = tid >> 5, tx = tid & 31;
            const int i0 = ty*4, d0 = tx*4;
            float4 accI[4], accX[4]; float accz[4];
            #pragma unroll
            for (int r = 0; r < 4; ++r) {
                accI[r] = make_float4(0.f,0.f,0.f,0.f);
                accX[r] = make_float4(0.f,0.f,0.f,0.f);
                accz[r] = 0.f;
            }
            for (int j = 0; j < Cn; ++j) {
                float4 vv = *(const float4*)&vB[j*128 + d0];
                #pragma unroll
                for (int r = 0; r < 4; ++r) {
                    float a = attnL[(i0+r)*66 + j];
                    accI[r].x += a*vv.x; accI[r].y += a*vv.y;
                    accI[r].z += a*vv.z; accI[r].w += a*vv.w;
                }
            }
            const float* qp = qin + (rowbase + i0)*Dn;
            for (int e0 = 0; e0 < Dn; e0 += 4) {
                float4 qv[4];
                #pragma unroll
                for (int r = 0; r < 4; ++r) qv[r] = *(const float4*)(qp + r*Dn + e0);
                #pragma unroll
                for (int ee = 0; ee < 4; ++ee) {
                    float4 sv = *(const float4*)&S[(e0+ee)*132 + d0];
                    float ze = zb[e0+ee];
                    #pragma unroll
                    for (int r = 0; r < 4; ++r) {
                        float qe = (ee==0)?qv[r].x:(ee==1)?qv[r].y:(ee==2)?qv[r].z:qv[r].w;
                        accX[r].x += qe*sv.x; accX[r].y += qe*sv.y;
                        accX[r].z += qe*sv.z; accX[r].w += qe*sv.w;
                        accz[r]   += qe*ze;
                    }
                }
            }
            #pragma unroll
            for (int r = 0; r < 4; ++r) {
                int i = i0 + r;
                float dq = ptab[i+1];
                float tz = fmaxf(izb[i] + dq*accz[r], 1.0f);
                float4 o;
                o.x = (accI[r].x + dq*accX[r].x)/tz;
                o.y = (accI[r].y + dq*accX[r].y)/tz;
                o.z = (accI[r].z + dq*accX[r].z)/tz;
                o.w = (accI[r].w + dq*accX[r].w)/tz;
                *(float4*)&out[(rowbase + i)*Dn + d0] = o;
            }
        }
        __syncthreads();   // all S reads done before update

        // ---- Phase C: S = lam^C * S + sum_c lam^{63-c} k_c (x) v_c ; z likewise ----
        {
            const int ty = tid >> 5, tx = tid & 31;
            const int e0 = ty*8, d0 = tx*4;
            const float lamC = ptab[64];
            float4 acc[8];
            #pragma unroll
            for (int a = 0; a < 8; ++a) {
                float4 sv = *(const float4*)&S[(e0+a)*132 + d0];
                acc[a].x = lamC*sv.x; acc[a].y = lamC*sv.y;
                acc[a].z = lamC*sv.z; acc[a].w = lamC*sv.w;
            }
            for (int c = 0; c < Cn; ++c) {
                float w = ptab[63-c];
                float4 vv = *(const float4*)&vB[c*128 + d0];
                float wx = w*vv.x, wy = w*vv.y, wz = w*vv.z, ww = w*vv.w;
                #pragma unroll
                for (int a = 0; a < 8; ++a) {
                    float ke = kT[(e0+a)*68 + c];
                    acc[a].x += ke*wx; acc[a].y += ke*wy;
                    acc[a].z += ke*wz; acc[a].w += ke*ww;
                }
            }
            #pragma unroll
            for (int a = 0; a < 8; ++a)
                *(float4*)&S[(e0+a)*132 + d0] = acc[a];
            if (tid < Dn) {
                float zn = lamC * zb[tid];
                for (int c = 0; c < Cn; ++c) zn += ptab[63-c]*kT[tid*68 + c];
                zb[tid] = zn;
            }
        }
    }
}

// -------------------------------------------------------------------------
extern "C" void kernel_launch(void* const* d_in, const int* in_sizes, int n_in,
                              void* d_out, int out_size, void* d_ws, size_t ws_size,
                              hipStream_t stream)
{
    const float* q  = (const float*)d_in[0];
    const float* k  = (const float*)d_in[1];
    const float* v  = (const float*)d_in[2];
    const float* ld = (const float*)d_in[3];
    float* out = (float*)d_out;

    // workspace layout (all f32): A | ksumg | Sg | zg   (~33.8 MB total)
    float* A     = (float*)d_ws;
    float* ksumg = A     + (size_t)Bn*NGn*Dn*Dn;
    float* Sg    = ksumg + (size_t)Bn*NGn*Dn;
    float* zg    = Sg    + (size_t)Bn*NGn*Dn*Dn;

    float* outState = out      + (size_t)Bn*Tn*Dn;   // [B,D,D]
    float* outZ     = outState + (size_t)Bn*Dn*Dn;   // [B,D]

    hipLaunchKernelGGL(k1_group_outer, dim3(NGn, Bn), dim3(256), 0, stream,
                       k, v, ld, A, ksumg);

    const int total2 = Bn*Dn*Dn + Bn*Dn;
    hipLaunchKernelGGL(k2_scan, dim3((total2 + 255)/256), dim3(256), 0, stream,
                       A, ksumg, ld, Sg, zg, outState, outZ);

    hipLaunchKernelGGL(k3_main, dim3(NGn, Bn), dim3(512), 0, stream,
                       q, k, v, ld, Sg, zg, out);
}

// Round 3
// 168.013 us; speedup vs baseline: 2.0198x; 2.0198x over previous
//
#include <hip/hip_runtime.h>
#include <math.h>

#define Bn  16
#define Tn  8192
#define Dn  128
#define Cn  64
#define Gn  8     // chunks per group
#define NGn 16    // groups per batch
#define GCn 512   // rows per group

typedef __attribute__((ext_vector_type(8)))  short short8v;
typedef __attribute__((ext_vector_type(16))) float f32x16;

#define AK  200   // A_cat stride (bf16), 64 rows: [attn(0..63) | Q2(64..191)]
#define BK  200   // B_cat stride (bf16), 128 rows: [d][ V^T(c:0..63) | S^T(64+e) ]
#define KDs 136   // Kd stride (bf16), 64 rows  (lam^{-(j+1)} * k, row-major)
#define KTs 72    // KwT stride (bf16), 128 rows ([e][c] = lam^{63-c} * k[c][e])
#define KFs 132   // kf stride (f32), 64 rows (k, then in-place prefix-decayed kappa)

__device__ __forceinline__ float sig_(float x){ return 1.0f/(1.0f+expf(-x)); }

__device__ __forceinline__ unsigned short f2bf(float f){
    __bf16 h = (__bf16)f;
    return __builtin_bit_cast(unsigned short, h);
}
__device__ __forceinline__ void st4(unsigned short* p, float a, float b, float c, float d){
    ushort4 u; u.x = f2bf(a); u.y = f2bf(b); u.z = f2bf(c); u.w = f2bf(d);
    *(ushort4*)p = u;   // ds_write_b64
}

// -------------------------------------------------------------------------
// K1: per (b,g): A_g[i][j] = sum_{r<512} lam^{511-r} k_r[i] v_r[j]  (f32)
//     ksum_g[i] accumulated from the staged wt*k tiles (no serial tail).
// -------------------------------------------------------------------------
__global__ __launch_bounds__(256)
void k1_group_outer(const float* __restrict__ kin, const float* __restrict__ vin,
                    const float* __restrict__ log_decay,
                    float* __restrict__ A, float* __restrict__ ksumg)
{
    const int g = blockIdx.x, b = blockIdx.y;
    const int tid = threadIdx.x;
    const float lam = sig_(log_decay[0]);

    __shared__ __align__(16) float kb[16*128];
    __shared__ __align__(16) float vb[16*128];
    __shared__ float wt[GCn];

    for (int i = tid; i < GCn; i += 256) wt[i] = powf(lam, (float)(GCn-1-i));

    const size_t base = ((size_t)b*Tn + (size_t)g*GCn)*Dn;
    const float* kg = kin + base;
    const float* vg = vin + base;

    const int ty = tid >> 4;
    const int tx = tid & 15;
    const int i0 = ty*8;
    const int j0 = tx*4;

    float4 acc0[8], acc1[8];
    #pragma unroll
    for (int a = 0; a < 8; ++a) {
        acc0[a] = make_float4(0.f,0.f,0.f,0.f);
        acc1[a] = make_float4(0.f,0.f,0.f,0.f);
    }
    float ks = 0.f;

    for (int r0 = 0; r0 < GCn; r0 += 16) {
        __syncthreads();
        #pragma unroll
        for (int it = 0; it < 8; ++it) {
            int idx = tid + it*256;
            int rr = idx >> 7, d = idx & 127;
            kb[rr*128+d] = wt[r0+rr] * kg[(size_t)(r0+rr)*Dn + d];
            vb[rr*128+d] =             vg[(size_t)(r0+rr)*Dn + d];
        }
        __syncthreads();
        #pragma unroll
        for (int rr = 0; rr < 16; ++rr) {
            float4 v0 = *(const float4*)&vb[rr*128 + j0];
            float4 v1 = *(const float4*)&vb[rr*128 + j0 + 64];
            #pragma unroll
            for (int a = 0; a < 8; ++a) {
                float kv = kb[rr*128 + i0 + a];
                acc0[a].x += kv*v0.x; acc0[a].y += kv*v0.y;
                acc0[a].z += kv*v0.z; acc0[a].w += kv*v0.w;
                acc1[a].x += kv*v1.x; acc1[a].y += kv*v1.y;
                acc1[a].z += kv*v1.z; acc1[a].w += kv*v1.w;
            }
        }
        if (tid < 128) {
            #pragma unroll
            for (int rr = 0; rr < 16; ++rr) ks += kb[rr*128 + tid];
        }
    }
    float* Ab = A + ((size_t)(b*NGn + g))*Dn*Dn;
    #pragma unroll
    for (int a = 0; a < 8; ++a) {
        *(float4*)&Ab[(size_t)(i0+a)*Dn + j0]      = acc0[a];
        *(float4*)&Ab[(size_t)(i0+a)*Dn + j0 + 64] = acc1[a];
    }
    if (tid < Dn) ksumg[((size_t)(b*NGn+g))*Dn + tid] = ks;
}

// -------------------------------------------------------------------------
// K2: exclusive scan over groups; final carry -> d_out state/z sections.
// -------------------------------------------------------------------------
__global__ __launch_bounds__(256)
void k2_scan(const float* __restrict__ A, const float* __restrict__ ksumg,
             const float* __restrict__ log_decay,
             float* __restrict__ Sg, float* __restrict__ zg,
             float* __restrict__ outState, float* __restrict__ outZ)
{
    const int idx = blockIdx.x*256 + threadIdx.x;
    const float lam = sig_(log_decay[0]);
    const float dG = powf(lam, (float)GCn);
    const int NSTATE = Bn*Dn*Dn;
    if (idx < NSTATE) {
        const int b = idx >> 14, ij = idx & 16383;
        float s = 0.f;
        #pragma unroll
        for (int g = 0; g < NGn; ++g) {
            size_t o = (((size_t)(b*NGn+g)) << 14) + ij;
            Sg[o] = s;
            s = dG*s + A[o];
        }
        outState[idx] = s;
    } else if (idx < NSTATE + Bn*Dn) {
        const int j = idx - NSTATE, b = j >> 7, d = j & 127;
        float s = 0.f;
        #pragma unroll
        for (int g = 0; g < NGn; ++g) {
            size_t o = (size_t)(b*NGn+g)*Dn + d;
            zg[o] = s;
            s = dG*s + ksumg[o];
        }
        outZ[j] = s;
    }
}

// -------------------------------------------------------------------------
// K3 (MFMA numerator + f32 denominator): per (b,g) block, 8 waves, 8 chunks.
//  P0: stage Q2->sA(bf16), Kd, KwT, V^T->sB, k(f32)->kf
//  P1: w0-1: kappa prefix scan (f32, in-place in kf)
//      w2-3: attn' = Kd x Q2^T -> mask -> sA bf16 (2 tiles each)
//      w4-7: Sacc = lam^64*Sacc + KwT x V^T (regs)
//  P2: all: stepB f32 dots iz=q.kappa_i, cz=lam^{i+1} q.z  THEN
//      out GEMM A_cat(64x192) @ B_cat^T
//  epi: out = (intra+cross) / max(max(iz,1)+cz,1)
//  P3: w4-7: Sacc -> sB S^T bf16;  tid<128: z = lam^64 z + kappa_63 (f32)
// -------------------------------------------------------------------------
__global__ __launch_bounds__(512)
void k3_mfma(const float* __restrict__ qin, const float* __restrict__ kin,
             const float* __restrict__ vin, const float* __restrict__ log_decay,
             const float* __restrict__ Sg, const float* __restrict__ zg,
             float* __restrict__ out)
{
    const int g = blockIdx.x, b = blockIdx.y;
    const int tid  = threadIdx.x;
    const int wid  = tid >> 6;
    const int lane = tid & 63;
    const int l31  = lane & 31;
    const int lhi  = lane >> 5;
    const float lam   = sig_(log_decay[0]);
    const float lam64 = powf(lam, 64.0f);

    __shared__ __align__(16) unsigned short sA [64*AK];    // 25.6 KB
    __shared__ __align__(16) unsigned short sB [128*BK];   // 51.2 KB
    __shared__ __align__(16) unsigned short sKd[64*KDs];   // 17.4 KB
    __shared__ __align__(16) unsigned short sKT[128*KTs];  // 18.4 KB
    __shared__ __align__(16) float kf[64*KFs];             // 33.8 KB
    __shared__ __align__(16) float zf[128];
    __shared__ __align__(16) float izb[64], czb[64];
    __shared__ float ptabs[66], ntabs[64];

    const int bg = b*NGn + g;

    // ---- init ----
    if (tid < 66)  ptabs[tid] = powf(lam, (float)tid);
    if (tid >= 66 && tid < 130) ntabs[tid-66] = powf(lam, -(float)(tid-65));
    if (tid < 128) zf[tid] = zg[(size_t)bg*Dn + tid];

    f32x16 sacc[4];
    if (wid >= 4) {
        const float* Sgp = Sg + ((size_t)bg << 14);
        const int er0 = (wid-4)*32;
        #pragma unroll
        for (int ct = 0; ct < 4; ++ct) {
            const int d = ct*32 + l31;
            #pragma unroll
            for (int r = 0; r < 16; ++r) {
                int e = er0 + (r&3) + 8*(r>>2) + 4*lhi;
                sacc[ct][r] = Sgp[e*Dn + d];
            }
            #pragma unroll
            for (int q = 0; q < 4; ++q) {
                int e0 = er0 + 8*q + 4*lhi;
                st4(&sB[d*BK + 64 + e0],
                    sacc[ct][4*q], sacc[ct][4*q+1], sacc[ct][4*q+2], sacc[ct][4*q+3]);
            }
        }
    }
    __syncthreads();

    for (int m = 0; m < Gn; ++m) {
        const size_t rowbase = (size_t)b*Tn + (size_t)(g*Gn + m)*Cn;

        // ================= P0: staging =================
        // Q2 = lam^{i+1} q  -> sA cols 64..191 (bf16)
        #pragma unroll
        for (int u = 0; u < 4; ++u) {
            int f = tid + 512*u;
            int i = f >> 5, c4 = (f & 31)*4;
            float4 qv = *(const float4*)&qin[(rowbase + i)*Dn + c4];
            float s = ptabs[i+1];
            st4(&sA[i*AK + 64 + c4], qv.x*s, qv.y*s, qv.z*s, qv.w*s);
        }
        // K 4x4 blocks -> kf (f32 copy), Kd (lam^{-(j+1)}), KwT (lam^{63-c}, transposed)
        {
            const int a4 = (tid >> 5)*4;       // row (c)
            const int b4 = (tid & 31)*4;       // col (e)
            float kv[4][4];
            #pragma unroll
            for (int u = 0; u < 4; ++u) {
                float4 t = *(const float4*)&kin[(rowbase + a4+u)*Dn + b4];
                kv[u][0]=t.x; kv[u][1]=t.y; kv[u][2]=t.z; kv[u][3]=t.w;
                *(float4*)&kf[(a4+u)*KFs + b4] = t;
            }
            #pragma unroll
            for (int u = 0; u < 4; ++u) {
                float s = ntabs[a4+u];
                st4(&sKd[(a4+u)*KDs + b4], kv[u][0]*s, kv[u][1]*s, kv[u][2]*s, kv[u][3]*s);
            }
            float w0 = ptabs[63-a4], w1 = ptabs[62-a4], w2 = ptabs[61-a4], w3 = ptabs[60-a4];
            #pragma unroll
            for (int e = 0; e < 4; ++e)
                st4(&sKT[(b4+e)*KTs + a4], kv[0][e]*w0, kv[1][e]*w1, kv[2][e]*w2, kv[3][e]*w3);
        }
        // V 4x4 blocks -> sB V^T region [d][c]
        {
            const int a4 = (tid >> 5)*4;       // row (c)
            const int b4 = (tid & 31)*4;       // col (d)
            float vv[4][4];
            #pragma unroll
            for (int u = 0; u < 4; ++u) {
                float4 t = *(const float4*)&vin[(rowbase + a4+u)*Dn + b4];
                vv[u][0]=t.x; vv[u][1]=t.y; vv[u][2]=t.z; vv[u][3]=t.w;
            }
            #pragma unroll
            for (int e = 0; e < 4; ++e)
                st4(&sB[(b4+e)*BK + a4], vv[0][e], vv[1][e], vv[2][e], vv[3][e]);
        }
        __syncthreads();   // barrier 1

        // ================= P1 =================
        if (wid < 2) {
            // kappa prefix scan, f32, in place: kf[j][d] := lam*kf[j-1][d] + k[j][d]
            const int d = tid;                 // 0..127
            float kap = 0.f;
            #pragma unroll 8
            for (int j = 0; j < Cn; ++j) {
                kap = lam*kap + kf[j*KFs + d];
                kf[j*KFs + d] = kap;
            }
        } else if (wid < 4) {
            // attn' tiles: D'[j][i] = sum_e Kd[j][e] * Q2[i][e]
            const int ic = (wid - 2)*32;
            #pragma unroll
            for (int jj = 0; jj < 2; ++jj) {
                const int jr = jj*32;
                f32x16 acc;
                #pragma unroll
                for (int r = 0; r < 16; ++r) acc[r] = 0.f;
                #pragma unroll
                for (int kk = 0; kk < 8; ++kk) {
                    short8v af = *(const short8v*)&sKd[(jr + l31)*KDs + kk*16 + lhi*8];
                    short8v bf = *(const short8v*)&sA [(ic + l31)*AK + 64 + kk*16 + lhi*8];
                    acc = __builtin_amdgcn_mfma_f32_32x32x16_bf16(af, bf, acc, 0, 0, 0);
                }
                const int i = ic + l31;
                #pragma unroll
                for (int q = 0; q < 4; ++q) {
                    int j0 = jr + 8*q + 4*lhi;
                    float v0 = (j0+0 <= i) ? acc[4*q+0] : 0.f;
                    float v1 = (j0+1 <= i) ? acc[4*q+1] : 0.f;
                    float v2 = (j0+2 <= i) ? acc[4*q+2] : 0.f;
                    float v3 = (j0+3 <= i) ? acc[4*q+3] : 0.f;
                    st4(&sA[i*AK + j0], v0, v1, v2, v3);
                }
            }
        } else {
            // state: Sacc = lam64*Sacc + KwT x V^T
            const int er0 = (wid-4)*32;
            #pragma unroll
            for (int ct = 0; ct < 4; ++ct)
                #pragma unroll
                for (int r = 0; r < 16; ++r) sacc[ct][r] *= lam64;
            #pragma unroll
            for (int kk = 0; kk < 4; ++kk) {
                short8v af = *(const short8v*)&sKT[(er0 + l31)*KTs + kk*16 + lhi*8];
                #pragma unroll
                for (int ct = 0; ct < 4; ++ct) {
                    short8v bf = *(const short8v*)&sB[(ct*32 + l31)*BK + kk*16 + lhi*8];
                    sacc[ct] = __builtin_amdgcn_mfma_f32_32x32x16_bf16(af, bf, sacc[ct], 0, 0, 0);
                }
            }
        }
        __syncthreads();   // barrier 2

        // ================= P2 =================
        // stepB: f32 denominator dots (overlaps with the GEMM below)
        {
            const int i = tid >> 3, seg = tid & 7;
            const float* qrow = &qin[(rowbase + i)*Dn + seg*16];
            float aI = 0.f, aZ = 0.f;
            #pragma unroll
            for (int u = 0; u < 4; ++u) {
                float4 qv = *(const float4*)(qrow + u*4);
                float4 kp = *(const float4*)&kf[i*KFs + seg*16 + u*4];
                float4 zv = *(const float4*)&zf[seg*16 + u*4];
                aI += qv.x*kp.x + qv.y*kp.y + qv.z*kp.z + qv.w*kp.w;
                aZ += qv.x*zv.x + qv.y*zv.y + qv.z*zv.z + qv.w*zv.w;
            }
            aI += __shfl_xor(aI, 1); aZ += __shfl_xor(aZ, 1);
            aI += __shfl_xor(aI, 2); aZ += __shfl_xor(aZ, 2);
            aI += __shfl_xor(aI, 4); aZ += __shfl_xor(aZ, 4);
            if (seg == 0) { izb[i] = aI; czb[i] = ptabs[i+1]*aZ; }
        }
        // out GEMM: D[i][d] = sum_k A_cat[i][k] * Bcat^T[d][k]
        const int r0 = (wid >> 2)*32;
        const int c0 = (wid & 3)*32;
        f32x16 oacc;
        #pragma unroll
        for (int r = 0; r < 16; ++r) oacc[r] = 0.f;
        #pragma unroll
        for (int kk = 0; kk < 12; ++kk) {
            short8v af = *(const short8v*)&sA[(r0 + l31)*AK + kk*16 + lhi*8];
            short8v bf = *(const short8v*)&sB[(c0 + l31)*BK + kk*16 + lhi*8];
            oacc = __builtin_amdgcn_mfma_f32_32x32x16_bf16(af, bf, oacc, 0, 0, 0);
        }
        __syncthreads();   // barrier 3: izb/czb visible, all sB reads done

        // epilogue
        #pragma unroll
        for (int r = 0; r < 16; ++r) {
            int t = r0 + (r&3) + 8*(r>>2) + 4*lhi;
            float tz = fmaxf(fmaxf(izb[t], 1.f) + czb[t], 1.f);
            float rv = __builtin_amdgcn_rcpf(tz);
            out[(rowbase + t)*Dn + c0 + l31] = oacc[r] * rv;
        }

        // ================= P3 =================
        if (wid >= 4) {
            const int er0 = (wid-4)*32;
            #pragma unroll
            for (int ct = 0; ct < 4; ++ct) {
                const int d = ct*32 + l31;
                #pragma unroll
                for (int q = 0; q < 4; ++q) {
                    int e0 = er0 + 8*q + 4*lhi;
                    st4(&sB[d*BK + 64 + e0],
                        sacc[ct][4*q], sacc[ct][4*q+1], sacc[ct][4*q+2], sacc[ct][4*q+3]);
                }
            }
        }
        if (tid < 128) {
            zf[tid] = lam64*zf[tid] + kf[63*KFs + tid];   // kappa_63 = chunk k_sum
        }
        __syncthreads();   // barrier 4
    }
}

// -------------------------------------------------------------------------
extern "C" void kernel_launch(void* const* d_in, const int* in_sizes, int n_in,
                              void* d_out, int out_size, void* d_ws, size_t ws_size,
                              hipStream_t stream)
{
    const float* q  = (const float*)d_in[0];
    const float* k  = (const float*)d_in[1];
    const float* v  = (const float*)d_in[2];
    const float* ld = (const float*)d_in[3];
    float* out = (float*)d_out;

    float* A     = (float*)d_ws;
    float* ksumg = A     + (size_t)Bn*NGn*Dn*Dn;
    float* Sg    = ksumg + (size_t)Bn*NGn*Dn;
    float* zg    = Sg    + (size_t)Bn*NGn*Dn*Dn;

    float* outState = out      + (size_t)Bn*Tn*Dn;
    float* outZ     = outState + (size_t)Bn*Dn*Dn;

    hipLaunchKernelGGL(k1_group_outer, dim3(NGn, Bn), dim3(256), 0, stream,
                       k, v, ld, A, ksumg);

    const int total2 = Bn*Dn*Dn + Bn*Dn;
    hipLaunchKernelGGL(k2_scan, dim3((total2 + 255)/256), dim3(256), 0, stream,
                       A, ksumg, ld, Sg, zg, outState, outZ);

    hipLaunchKernelGGL(k3_mfma, dim3(NGn, Bn), dim3(512), 0, stream,
                       q, k, v, ld, Sg, zg, out);
}

// Round 4
// 99.587 us; speedup vs baseline: 3.4076x; 1.6871x over previous
//
#include <hip/hip_runtime.h>
#include <math.h>

#define Bn  16
#define Tn  8192
#define Dn  128
#define Cn  64
#define Gn  8     // chunks per group
#define NGn 16    // groups per batch
#define GCn 512   // rows per group

typedef __attribute__((ext_vector_type(8)))  short short8v;
typedef __attribute__((ext_vector_type(16))) float f32x16;

#define AK  200   // A_cat stride (bf16), 64 rows: [attn(0..63) | Q2(64..191)]
#define BK  200   // B_cat stride (bf16), 128 rows: [d][ V^T(c:0..63) | S^T(64+e) ]
#define KDs 136   // Kd stride (bf16), 64 rows  (lam^{-(j+1)} * k, row-major)
#define KTs 72    // KwT stride (bf16), 128 rows ([e][c] = lam^{63-c} * k[c][e])
#define KFs 132   // kf stride (f32), 64 rows (k, then in-place prefix-decayed kappa)
#define K1s 72    // k1 kT/vT stride (bf16), 128 rows x 64 k-cols

__device__ __forceinline__ float sig_(float x){ return 1.0f/(1.0f+expf(-x)); }

__device__ __forceinline__ unsigned short f2bf(float f){
    __bf16 h = (__bf16)f;
    return __builtin_bit_cast(unsigned short, h);
}
__device__ __forceinline__ void st4(unsigned short* p, float a, float b, float c, float d){
    ushort4 u; u.x = f2bf(a); u.y = f2bf(b); u.z = f2bf(c); u.w = f2bf(d);
    *(ushort4*)p = u;   // ds_write_b64
}

// -------------------------------------------------------------------------
// K1 (MFMA): per (b,g): A_g = (Kw)^T @ V  (M=N=128, K=512, bf16 in / f32 out)
//   Kw[r][i] = lam^{511-r} * k[r][i].  ksum_g[i] = sum_r Kw[r][i]  kept f32
//   via register partials during staging (denominator path needs f32).
// -------------------------------------------------------------------------
__global__ __launch_bounds__(512)
void k1_mfma(const float* __restrict__ kin, const float* __restrict__ vin,
             const float* __restrict__ log_decay,
             float* __restrict__ A, float* __restrict__ ksumg)
{
    const int g = blockIdx.x, b = blockIdx.y;
    const int tid  = threadIdx.x;
    const int wid  = tid >> 6;
    const int lane = tid & 63;
    const int l31  = lane & 31;
    const int lhi  = lane >> 5;
    const float lam = sig_(log_decay[0]);

    __shared__ __align__(16) unsigned short kT[128*K1s];  // [i][r] 18.4 KB
    __shared__ __align__(16) unsigned short vT[128*K1s];  // [j][r] 18.4 KB
    __shared__ float wt[GCn];                             // 2 KB
    __shared__ __align__(16) float ps[16*132];            // 8.4 KB ksum partials

    wt[tid] = powf(lam, (float)(GCn-1 - tid));            // blockDim == 512 == GCn

    const size_t base = ((size_t)b*Tn + (size_t)g*GCn)*Dn;
    const int rb = tid >> 5;          // row block 0..15 (4 rows each)
    const int cb = (tid & 31)*4;      // col 0..124

    f32x16 acc[2];
    #pragma unroll
    for (int p = 0; p < 2; ++p)
        #pragma unroll
        for (int r = 0; r < 16; ++r) acc[p][r] = 0.f;
    float ksp[4] = {0.f, 0.f, 0.f, 0.f};

    // prologue: issue loads for tile 0
    float kv[4][4], vv[4][4];
    {
        const float* kp = kin + base;
        const float* vp = vin + base;
        #pragma unroll
        for (int u = 0; u < 4; ++u) {
            float4 t4 = *(const float4*)&kp[(size_t)(rb*4+u)*Dn + cb];
            kv[u][0]=t4.x; kv[u][1]=t4.y; kv[u][2]=t4.z; kv[u][3]=t4.w;
            float4 s4 = *(const float4*)&vp[(size_t)(rb*4+u)*Dn + cb];
            vv[u][0]=s4.x; vv[u][1]=s4.y; vv[u][2]=s4.z; vv[u][3]=s4.w;
        }
    }
    __syncthreads();   // wt visible

    const int tr0 = (wid >> 2)*2;     // tile-row pair base (0 or 2)
    const int tc  = (wid & 3)*32;     // tile col base

    for (int t = 0; t < 8; ++t) {
        // ---- stage regs(t) -> LDS (transpose + weight + bf16), ksum f32 partials ----
        const int r0 = rb*4;          // row within tile
        float w0 = wt[t*64 + r0+0], w1 = wt[t*64 + r0+1];
        float w2 = wt[t*64 + r0+2], w3 = wt[t*64 + r0+3];
        #pragma unroll
        for (int e = 0; e < 4; ++e) {
            float a0 = kv[0][e]*w0, a1 = kv[1][e]*w1, a2 = kv[2][e]*w2, a3 = kv[3][e]*w3;
            ksp[e] += (a0 + a1) + (a2 + a3);
            st4(&kT[(cb+e)*K1s + r0], a0, a1, a2, a3);
            st4(&vT[(cb+e)*K1s + r0], vv[0][e], vv[1][e], vv[2][e], vv[3][e]);
        }
        __syncthreads();              // tile t staged

        // ---- issue loads for t+1 (fly during MFMA) ----
        if (t < 7) {
            const float* kp = kin + base + (size_t)(t+1)*64*Dn;
            const float* vp = vin + base + (size_t)(t+1)*64*Dn;
            #pragma unroll
            for (int u = 0; u < 4; ++u) {
                float4 t4 = *(const float4*)&kp[(size_t)(rb*4+u)*Dn + cb];
                kv[u][0]=t4.x; kv[u][1]=t4.y; kv[u][2]=t4.z; kv[u][3]=t4.w;
                float4 s4 = *(const float4*)&vp[(size_t)(rb*4+u)*Dn + cb];
                vv[u][0]=s4.x; vv[u][1]=s4.y; vv[u][2]=s4.z; vv[u][3]=s4.w;
            }
        }

        // ---- MFMA on tile t ----
        #pragma unroll
        for (int kk = 0; kk < 4; ++kk) {
            short8v bf = *(const short8v*)&vT[(tc + l31)*K1s + kk*16 + lhi*8];
            #pragma unroll
            for (int p = 0; p < 2; ++p) {
                short8v af = *(const short8v*)&kT[((tr0+p)*32 + l31)*K1s + kk*16 + lhi*8];
                acc[p] = __builtin_amdgcn_mfma_f32_32x32x16_bf16(af, bf, acc[p], 0, 0, 0);
            }
        }
        __syncthreads();              // LDS reads done before next staging write
    }

    // ---- write A (f32) ----
    float* Ab = A + ((size_t)(b*NGn + g))*Dn*Dn;
    #pragma unroll
    for (int p = 0; p < 2; ++p) {
        #pragma unroll
        for (int r = 0; r < 16; ++r) {
            int i = (tr0+p)*32 + (r&3) + 8*(r>>2) + 4*lhi;
            Ab[(size_t)i*Dn + tc + l31] = acc[p][r];
        }
    }

    // ---- ksum reduction (f32) ----
    *(float4*)&ps[rb*132 + cb] = make_float4(ksp[0], ksp[1], ksp[2], ksp[3]);
    __syncthreads();
    if (tid < Dn) {
        float s = 0.f;
        #pragma unroll
        for (int q = 0; q < 16; ++q) s += ps[q*132 + tid];
        ksumg[((size_t)(b*NGn+g))*Dn + tid] = s;
    }
}

// -------------------------------------------------------------------------
// K2: exclusive scan over groups; final carry -> d_out state/z sections.
// -------------------------------------------------------------------------
__global__ __launch_bounds__(256)
void k2_scan(const float* __restrict__ A, const float* __restrict__ ksumg,
             const float* __restrict__ log_decay,
             float* __restrict__ Sg, float* __restrict__ zg,
             float* __restrict__ outState, float* __restrict__ outZ)
{
    const int idx = blockIdx.x*256 + threadIdx.x;
    const float lam = sig_(log_decay[0]);
    const float dG = powf(lam, (float)GCn);
    const int NSTATE = Bn*Dn*Dn;
    if (idx < NSTATE) {
        const int b = idx >> 14, ij = idx & 16383;
        float s = 0.f;
        #pragma unroll
        for (int g = 0; g < NGn; ++g) {
            size_t o = (((size_t)(b*NGn+g)) << 14) + ij;
            Sg[o] = s;
            s = dG*s + A[o];
        }
        outState[idx] = s;
    } else if (idx < NSTATE + Bn*Dn) {
        const int j = idx - NSTATE, b = j >> 7, d = j & 127;
        float s = 0.f;
        #pragma unroll
        for (int g = 0; g < NGn; ++g) {
            size_t o = (size_t)(b*NGn+g)*Dn + d;
            zg[o] = s;
            s = dG*s + ksumg[o];
        }
        outZ[j] = s;
    }
}

// -------------------------------------------------------------------------
// K3 (MFMA numerator + f32 denominator): per (b,g) block, 8 waves, 8 chunks.
// -------------------------------------------------------------------------
__global__ __launch_bounds__(512)
void k3_mfma(const float* __restrict__ qin, const float* __restrict__ kin,
             const float* __restrict__ vin, const float* __restrict__ log_decay,
             const float* __restrict__ Sg, const float* __restrict__ zg,
             float* __restrict__ out)
{
    const int g = blockIdx.x, b = blockIdx.y;
    const int tid  = threadIdx.x;
    const int wid  = tid >> 6;
    const int lane = tid & 63;
    const int l31  = lane & 31;
    const int lhi  = lane >> 5;
    const float lam   = sig_(log_decay[0]);
    const float lam64 = powf(lam, 64.0f);

    __shared__ __align__(16) unsigned short sA [64*AK];    // 25.6 KB
    __shared__ __align__(16) unsigned short sB [128*BK];   // 51.2 KB
    __shared__ __align__(16) unsigned short sKd[64*KDs];   // 17.4 KB
    __shared__ __align__(16) unsigned short sKT[128*KTs];  // 18.4 KB
    __shared__ __align__(16) float kf[64*KFs];             // 33.8 KB
    __shared__ __align__(16) float zf[128];
    __shared__ __align__(16) float izb[64], czb[64];
    __shared__ float ptabs[66], ntabs[64];

    const int bg = b*NGn + g;

    // ---- init ----
    if (tid < 66)  ptabs[tid] = powf(lam, (float)tid);
    if (tid >= 66 && tid < 130) ntabs[tid-66] = powf(lam, -(float)(tid-65));
    if (tid < 128) zf[tid] = zg[(size_t)bg*Dn + tid];

    f32x16 sacc[4];
    if (wid >= 4) {
        const float* Sgp = Sg + ((size_t)bg << 14);
        const int er0 = (wid-4)*32;
        #pragma unroll
        for (int ct = 0; ct < 4; ++ct) {
            const int d = ct*32 + l31;
            #pragma unroll
            for (int r = 0; r < 16; ++r) {
                int e = er0 + (r&3) + 8*(r>>2) + 4*lhi;
                sacc[ct][r] = Sgp[e*Dn + d];
            }
            #pragma unroll
            for (int q = 0; q < 4; ++q) {
                int e0 = er0 + 8*q + 4*lhi;
                st4(&sB[d*BK + 64 + e0],
                    sacc[ct][4*q], sacc[ct][4*q+1], sacc[ct][4*q+2], sacc[ct][4*q+3]);
            }
        }
    }
    __syncthreads();

    for (int m = 0; m < Gn; ++m) {
        const size_t rowbase = (size_t)b*Tn + (size_t)(g*Gn + m)*Cn;

        // ================= P0: staging =================
        #pragma unroll
        for (int u = 0; u < 4; ++u) {
            int f = tid + 512*u;
            int i = f >> 5, c4 = (f & 31)*4;
            float4 qv = *(const float4*)&qin[(rowbase + i)*Dn + c4];
            float s = ptabs[i+1];
            st4(&sA[i*AK + 64 + c4], qv.x*s, qv.y*s, qv.z*s, qv.w*s);
        }
        {
            const int a4 = (tid >> 5)*4;       // row (c)
            const int b4 = (tid & 31)*4;       // col (e)
            float kv[4][4];
            #pragma unroll
            for (int u = 0; u < 4; ++u) {
                float4 t = *(const float4*)&kin[(rowbase + a4+u)*Dn + b4];
                kv[u][0]=t.x; kv[u][1]=t.y; kv[u][2]=t.z; kv[u][3]=t.w;
                *(float4*)&kf[(a4+u)*KFs + b4] = t;
            }
            #pragma unroll
            for (int u = 0; u < 4; ++u) {
                float s = ntabs[a4+u];
                st4(&sKd[(a4+u)*KDs + b4], kv[u][0]*s, kv[u][1]*s, kv[u][2]*s, kv[u][3]*s);
            }
            float w0 = ptabs[63-a4], w1 = ptabs[62-a4], w2 = ptabs[61-a4], w3 = ptabs[60-a4];
            #pragma unroll
            for (int e = 0; e < 4; ++e)
                st4(&sKT[(b4+e)*KTs + a4], kv[0][e]*w0, kv[1][e]*w1, kv[2][e]*w2, kv[3][e]*w3);
        }
        {
            const int a4 = (tid >> 5)*4;       // row (c)
            const int b4 = (tid & 31)*4;       // col (d)
            float vv[4][4];
            #pragma unroll
            for (int u = 0; u < 4; ++u) {
                float4 t = *(const float4*)&vin[(rowbase + a4+u)*Dn + b4];
                vv[u][0]=t.x; vv[u][1]=t.y; vv[u][2]=t.z; vv[u][3]=t.w;
            }
            #pragma unroll
            for (int e = 0; e < 4; ++e)
                st4(&sB[(b4+e)*BK + a4], vv[0][e], vv[1][e], vv[2][e], vv[3][e]);
        }
        __syncthreads();   // barrier 1

        // ================= P1 =================
        if (wid < 2) {
            const int d = tid;                 // 0..127
            float kap = 0.f;
            #pragma unroll 8
            for (int j = 0; j < Cn; ++j) {
                kap = lam*kap + kf[j*KFs + d];
                kf[j*KFs + d] = kap;
            }
        } else if (wid < 4) {
            const int ic = (wid - 2)*32;
            #pragma unroll
            for (int jj = 0; jj < 2; ++jj) {
                const int jr = jj*32;
                f32x16 acc;
                #pragma unroll
                for (int r = 0; r < 16; ++r) acc[r] = 0.f;
                #pragma unroll
                for (int kk = 0; kk < 8; ++kk) {
                    short8v af = *(const short8v*)&sKd[(jr + l31)*KDs + kk*16 + lhi*8];
                    short8v bf = *(const short8v*)&sA [(ic + l31)*AK + 64 + kk*16 + lhi*8];
                    acc = __builtin_amdgcn_mfma_f32_32x32x16_bf16(af, bf, acc, 0, 0, 0);
                }
                const int i = ic + l31;
                #pragma unroll
                for (int q = 0; q < 4; ++q) {
                    int j0 = jr + 8*q + 4*lhi;
                    float v0 = (j0+0 <= i) ? acc[4*q+0] : 0.f;
                    float v1 = (j0+1 <= i) ? acc[4*q+1] : 0.f;
                    float v2 = (j0+2 <= i) ? acc[4*q+2] : 0.f;
                    float v3 = (j0+3 <= i) ? acc[4*q+3] : 0.f;
                    st4(&sA[i*AK + j0], v0, v1, v2, v3);
                }
            }
        } else {
            const int er0 = (wid-4)*32;
            #pragma unroll
            for (int ct = 0; ct < 4; ++ct)
                #pragma unroll
                for (int r = 0; r < 16; ++r) sacc[ct][r] *= lam64;
            #pragma unroll
            for (int kk = 0; kk < 4; ++kk) {
                short8v af = *(const short8v*)&sKT[(er0 + l31)*KTs + kk*16 + lhi*8];
                #pragma unroll
                for (int ct = 0; ct < 4; ++ct) {
                    short8v bf = *(const short8v*)&sB[(ct*32 + l31)*BK + kk*16 + lhi*8];
                    sacc[ct] = __builtin_amdgcn_mfma_f32_32x32x16_bf16(af, bf, sacc[ct], 0, 0, 0);
                }
            }
        }
        __syncthreads();   // barrier 2

        // ================= P2 =================
        {
            const int i = tid >> 3, seg = tid & 7;
            const float* qrow = &qin[(rowbase + i)*Dn + seg*16];
            float aI = 0.f, aZ = 0.f;
            #pragma unroll
            for (int u = 0; u < 4; ++u) {
                float4 qv = *(const float4*)(qrow + u*4);
                float4 kp = *(const float4*)&kf[i*KFs + seg*16 + u*4];
                float4 zv = *(const float4*)&zf[seg*16 + u*4];
                aI += qv.x*kp.x + qv.y*kp.y + qv.z*kp.z + qv.w*kp.w;
                aZ += qv.x*zv.x + qv.y*zv.y + qv.z*zv.z + qv.w*zv.w;
            }
            aI += __shfl_xor(aI, 1); aZ += __shfl_xor(aZ, 1);
            aI += __shfl_xor(aI, 2); aZ += __shfl_xor(aZ, 2);
            aI += __shfl_xor(aI, 4); aZ += __shfl_xor(aZ, 4);
            if (seg == 0) { izb[i] = aI; czb[i] = ptabs[i+1]*aZ; }
        }
        const int r0 = (wid >> 2)*32;
        const int c0 = (wid & 3)*32;
        f32x16 oacc;
        #pragma unroll
        for (int r = 0; r < 16; ++r) oacc[r] = 0.f;
        #pragma unroll
        for (int kk = 0; kk < 12; ++kk) {
            short8v af = *(const short8v*)&sA[(r0 + l31)*AK + kk*16 + lhi*8];
            short8v bf = *(const short8v*)&sB[(c0 + l31)*BK + kk*16 + lhi*8];
            oacc = __builtin_amdgcn_mfma_f32_32x32x16_bf16(af, bf, oacc, 0, 0, 0);
        }
        __syncthreads();   // barrier 3

        #pragma unroll
        for (int r = 0; r < 16; ++r) {
            int t = r0 + (r&3) + 8*(r>>2) + 4*lhi;
            float tz = fmaxf(fmaxf(izb[t], 1.f) + czb[t], 1.f);
            float rv = __builtin_amdgcn_rcpf(tz);
            out[(rowbase + t)*Dn + c0 + l31] = oacc[r] * rv;
        }

        // ================= P3 =================
        if (wid >= 4) {
            const int er0 = (wid-4)*32;
            #pragma unroll
            for (int ct = 0; ct < 4; ++ct) {
                const int d = ct*32 + l31;
                #pragma unroll
                for (int q = 0; q < 4; ++q) {
                    int e0 = er0 + 8*q + 4*lhi;
                    st4(&sB[d*BK + 64 + e0],
                        sacc[ct][4*q], sacc[ct][4*q+1], sacc[ct][4*q+2], sacc[ct][4*q+3]);
                }
            }
        }
        if (tid < 128) {
            zf[tid] = lam64*zf[tid] + kf[63*KFs + tid];   // kappa_63 = chunk k_sum
        }
        __syncthreads();   // barrier 4
    }
}

// -------------------------------------------------------------------------
extern "C" void kernel_launch(void* const* d_in, const int* in_sizes, int n_in,
                              void* d_out, int out_size, void* d_ws, size_t ws_size,
                              hipStream_t stream)
{
    const float* q  = (const float*)d_in[0];
    const float* k  = (const float*)d_in[1];
    const float* v  = (const float*)d_in[2];
    const float* ld = (const float*)d_in[3];
    float* out = (float*)d_out;

    float* A     = (float*)d_ws;
    float* ksumg = A     + (size_t)Bn*NGn*Dn*Dn;
    float* Sg    = ksumg + (size_t)Bn*NGn*Dn;
    float* zg    = Sg    + (size_t)Bn*NGn*Dn*Dn;

    float* outState = out      + (size_t)Bn*Tn*Dn;
    float* outZ     = outState + (size_t)Bn*Dn*Dn;

    hipLaunchKernelGGL(k1_mfma, dim3(NGn, Bn), dim3(512), 0, stream,
                       k, v, ld, A, ksumg);

    const int total2 = Bn*Dn*Dn + Bn*Dn;
    hipLaunchKernelGGL(k2_scan, dim3((total2 + 255)/256), dim3(256), 0, stream,
                       A, ksumg, ld, Sg, zg, outState, outZ);

    hipLaunchKernelGGL(k3_mfma, dim3(NGn, Bn), dim3(512), 0, stream,
                       q, k, v, ld, Sg, zg, out);
}